// Round 6
// baseline (272.173 us; speedup 1.0000x reference)
//
#include <hip/hip_runtime.h>

// Causal depthwise conv1d: y[b,s,h] = sum_j x[b, s-(K-1)+j, h] * w[h,j], * mask[b,s]
// B=4, S=4096, H=2048, K=4, fp32. Memory-bound.
//
// History: R3/R5/R6 ~82us (2.6-2.75 TB/s), R7 1-row blocks 163us, R8 batch-11
// loads ~78us. Little's law post-mortem: in-flight bytes were NEVER the limit
// (26KB/CU >= 15KB needed). Remaining structural gap vs the 6.3-6.6 TB/s
// copy/fill kernels: (1) independent loop iterations (no carried dep, no
// batch-drain convoy, no block churn) -> continuous issue; (2) rolling
// CONTIGUOUS frontier, few streams per HBM channel.
// R9: persistent grid-stride copy-shaped kernel. 2048x256, flat float4 space,
// 16 iters/thread. 4 independent loads/iter; halo re-reads hit same-XCD L2
// (chunked XCD swizzle -> each XCD sweeps a contiguous ~1MB rolling window).
// h4 loop-invariant -> weights loaded once. Mask via readfirstlane -> s_load.
// Predict: dur <=60us, BW >=4 TB/s, FETCH 100-160MB (>=350MB = L2-leg failed).

constexpr int B_   = 4;
constexpr int S_   = 4096;
constexpr int H_   = 2048;
constexpr int H4_  = H_ / 4;                   // 512 float4 per row
constexpr int TPB  = 256;
constexpr int NBLK = 2048;
constexpr int NXCD = 8;
constexpr long TOT4   = (long)B_ * S_ * H4_;   // 8,388,608 float4 elements
constexpr long STRIDE = (long)NBLK * TPB;      // 524,288 -> 16 iters/thread

typedef float f32x4 __attribute__((ext_vector_type(4)));

__global__ __launch_bounds__(TPB, 6) void budgie_dwconv1d_kernel(
    const float* __restrict__ x,     // [B,S,H]
    const float* __restrict__ w,     // [H,K]
    const float* __restrict__ mask,  // [B,S]
    float* __restrict__ y)           // [B,S,H]
{
    // Chunked XCD swizzle (bijective, NBLK%NXCD==0): XCD k owns work-ids
    // [k*256, k*256+255] -> each XCD sweeps a contiguous 1MB rolling window,
    // so halo rows 8-24KB behind the frontier are same-XCD L2 hits.
    const int wid = (blockIdx.x & (NXCD - 1)) * (NBLK / NXCD) + (blockIdx.x >> 3);

    const float4* __restrict__ x4 = (const float4*)x;
    const float4* __restrict__ w4 = (const float4*)w;
    f32x4* __restrict__ y4 = (f32x4*)y;

    const long g0 = (long)wid * TPB + threadIdx.x;

    // h4 = g & 511 is invariant across iterations (STRIDE % 512 == 0):
    // load the 4 taps once.
    const int h4    = (int)(g0 & (H4_ - 1));
    const int hbase = h4 * 4;
    const float4 w0 = w4[hbase + 0];
    const float4 w1 = w4[hbase + 1];
    const float4 w2 = w4[hbase + 2];
    const float4 w3 = w4[hbase + 3];

    const float4 zero4 = make_float4(0.f, 0.f, 0.f, 0.f);

    #pragma unroll 2
    for (long g = g0; g < TOT4; g += STRIDE) {
        const int row = (int)(g >> 9);           // b*S + s   (uniform per block)
        const int s   = row & (S_ - 1);

        // 4 independent loads; iterations are independent too (no carried dep,
        // __restrict__ lets the scheduler overlap across iterations).
        const float4 x0 = x4[g];
        float4 x1, x2, x3;
        if (s >= 3) {                            // uniform branch; hot path: no selects
            x1 = x4[g - 1 * H4_];
            x2 = x4[g - 2 * H4_];
            x3 = x4[g - 3 * H4_];
        } else {
            x1 = (s >= 1) ? x4[g - 1 * H4_] : zero4;
            x2 = (s >= 2) ? x4[g - 2 * H4_] : zero4;
            x3 = zero4;
        }

        // row is block-uniform -> scalarize the mask load (s_load, off VMEM path).
        const int  row_u = __builtin_amdgcn_readfirstlane(row);
        const float m    = mask[row_u];

        f32x4 o;
        o.x = fmaf(x3.x, w0.x, fmaf(x2.x, w0.y, fmaf(x1.x, w0.z, x0.x * w0.w)));
        o.y = fmaf(x3.y, w1.x, fmaf(x2.y, w1.y, fmaf(x1.y, w1.z, x0.y * w1.w)));
        o.z = fmaf(x3.z, w2.x, fmaf(x2.z, w2.y, fmaf(x1.z, w2.z, x0.z * w2.w)));
        o.w = fmaf(x3.w, w3.x, fmaf(x2.w, w3.y, fmaf(x1.w, w3.z, x0.w * w3.w)));
        o.x *= m; o.y *= m; o.z *= m; o.w *= m;

        __builtin_nontemporal_store(o, &y4[g]);
    }
}

extern "C" void kernel_launch(void* const* d_in, const int* in_sizes, int n_in,
                              void* d_out, int out_size, void* d_ws, size_t ws_size,
                              hipStream_t stream) {
    const float* x    = (const float*)d_in[0];   // hidden_states [B,S,H]
    const float* w    = (const float*)d_in[1];   // weight [H,K]
    const float* mask = (const float*)d_in[2];   // attention_mask_2d [B,S]
    float* y = (float*)d_out;

    budgie_dwconv1d_kernel<<<dim3(NBLK), TPB, 0, stream>>>(x, w, mask, y);
}